// Round 9
// baseline (312.036 us; speedup 1.0000x reference)
//
#include <hip/hip_runtime.h>
#include <hip/hip_cooperative_groups.h>

typedef unsigned short u16;
typedef u16 u16x8 __attribute__((ext_vector_type(8)));
typedef _Float16 half2 __attribute__((ext_vector_type(2)));
typedef _Float16 h8v __attribute__((ext_vector_type(8)));
typedef float f4v __attribute__((ext_vector_type(4)));
typedef unsigned int u32;
typedef u32 u32x4 __attribute__((ext_vector_type(4)));

union H8 { h8v v; half2 p[4]; };

// ---------- bf16 helpers ----------
static __device__ __forceinline__ float bf2f(u16 u) {
    union { unsigned int i; float f; } v;
    v.i = ((unsigned int)u) << 16;
    return v.f;
}
static __device__ __forceinline__ u16 f2bf(float f) {
    union { float f; unsigned int i; } v;
    v.f = f;
    unsigned int x = v.i;
    x += 0x7fffu + ((x >> 16) & 1u);   // RNE
    return (u16)(x >> 16);
}
static __device__ __forceinline__ float gld(int dt, const void* p, int i) {
    return dt ? ((const float*)p)[i] : bf2f(((const u16*)p)[i]);
}
static __device__ __forceinline__ int detect_dt(const void* coords) {
    u16 v = ((const u16*)coords)[threadIdx.x & 63];
    int e = (v >> 7) & 0xFF;
    bool inr = (e >= 90) && (e <= 126);
    unsigned long long m = __ballot(inr);
    return (__popcll(m) >= 56) ? 0 : 1;   // 0=bf16, 1=f32
}
static __device__ __forceinline__ half2 pk(float a, float b) {
    return __builtin_bit_cast(half2, __builtin_amdgcn_cvt_pkrtz(a, b));
}

// LDS-only ordering for single-wave workgroups: waits DS ops WITHOUT
// draining vmcnt — REQUIRED so the prefetched plane/vol gathers stay in
// flight across the LDS phases (threadfence_block's vmcnt(0) would kill
// the software pipeline).
static __device__ __forceinline__ void lds_wait() {
    asm volatile("s_waitcnt lgkmcnt(0)" ::: "memory");
}

// ---------- ws layout (bytes) ----------
#define WF_OFF        64u
#define PLANES_S_OFF  34304u         // 3*524288 u16
#define VOL_S_OFF     3180032u       // 2097152 u16
#define LINES_S_OFF   7374336u       // 12288 u16
#define PART_OFF      7398912u       // 256*4096 u16 = 2 MB
#define TOT_OFF       9496064u       // 4096 u32
#define REC_OFF       9512448u       // 16*M (16B-aligned)
// record per sorted position: {u32 p; u32 x|y<<16; u32 z; u32 pad}

#define NBUCK 4096
#define HBLOCKS 256

// =====================================================================
// spatial key
// =====================================================================
static __device__ __forceinline__ int make_key3(float x, float y, float z) {
    int kx = min(max((int)((x + 1.0f) * 8.0f), 0), 15);
    int ky = min(max((int)((y + 1.0f) * 8.0f), 0), 15);
    int kz = min(max((int)((z + 1.0f) * 8.0f), 0), 15);
    return (kz * 16 + ky) * 16 + kx;
}
static __device__ __forceinline__ int make_key(int dt, const void* coords, int p) {
    return make_key3(gld(dt, coords, p * 3 + 0), gld(dt, coords, p * 3 + 1),
                     gld(dt, coords, p * 3 + 2));
}

// =====================================================================
// weight packing (f16 MFMA layouts)
// =====================================================================
static __device__ __forceinline__ void weights_work(
    int dt, int r,
    const void* Wx, const void* bx, const void* Wy, const void* by,
    const void* Wz, const void* bz, const void* W1, const void* b1,
    const void* W2, const void* b2, float* wbase)
{
    _Float16* WtH = (_Float16*)wbase;
    float*    bv  = wbase + 1536;
    _Float16* W1H = (_Float16*)(wbase + 1632);
    float*    b1v = wbase + 5728;
    float*    W2v = wbase + 5856;
    float*    b2v = wbase + 5984;
    if (r < 3072) {
        int m = r >> 10, idx = r & 1023;
        int o = idx >> 5, c = idx & 31;
        const void* s = (m == 0) ? Wx : (m == 1) ? Wy : Wz;
        WtH[r] = (_Float16)gld(dt, s, c * 32 + o);   // Wt[m][o][c] = W[c][o]
    } else if (r < 3168) {
        int q2 = r - 3072;
        int m = q2 >> 5, c = q2 & 31;
        const void* s = (m == 0) ? bx : (m == 1) ? by : bz;
        bv[q2] = gld(dt, s, c);
    } else if (r < 11360) {
        int idx = r - 3168;                 // j*64 + i
        int j = idx >> 6, i = idx & 63;
        W1H[idx] = (i < 40) ? (_Float16)gld(dt, W1, i * 128 + j) : (_Float16)0.0f;
    } else if (r < 11488) {
        b1v[r - 11360] = gld(dt, b1, r - 11360);
    } else if (r < 11616) {
        W2v[r - 11488] = gld(dt, W2, r - 11488);
    } else if (r == 11616) {
        b2v[0] = gld(dt, b2, 0);
    }
}

// =====================================================================
// fused prep: grid transpose (0..1797) + weights (1798..1843)
//           + histogram partials u16, plain stores (1844..2099)
// =====================================================================
__global__ __launch_bounds__(256) void kp_prep_all(
    const void* __restrict__ coords,
    const void* __restrict__ lx, const void* __restrict__ ly,
    const void* __restrict__ lz,
    const void* __restrict__ pxy, const void* __restrict__ pyz,
    const void* __restrict__ pxz, const void* __restrict__ vol,
    const void* __restrict__ Wx, const void* __restrict__ bx,
    const void* __restrict__ Wy, const void* __restrict__ by,
    const void* __restrict__ Wz, const void* __restrict__ bz,
    const void* __restrict__ W1, const void* __restrict__ b1,
    const void* __restrict__ W2, const void* __restrict__ b2,
    float* __restrict__ wbase,
    u16* __restrict__ planes_s, u16* __restrict__ vol_s,
    u16* __restrict__ lines_s, u16* __restrict__ part, int M)
{
    __shared__ unsigned int lh[NBUCK];
    int dt = detect_dt(coords);
    int blk = blockIdx.x;
    if (blk < 1798) {
        int t = blk * 256 + threadIdx.x;   // [0, 460288)
        u16x8 v;
        if (t < 196608) {                 // planes: 8 consecutive out u16
            int o = t * 8;
            int pl = o >> 19;
            int r  = o & 524287;
            int pos = r >> 5, c0 = r & 31;
            const void* src = (pl == 0) ? pxy : (pl == 1) ? pyz : pxz;
#pragma unroll
            for (int i = 0; i < 8; ++i)
                v[i] = dt ? f2bf(((const float*)src)[(c0 + i) * 16384 + pos])
                          : ((const u16*)src)[(c0 + i) * 16384 + pos];
            *(u16x8*)(planes_s + o) = v;
        } else if (t < 458752) {          // volume: thread = one pos, 8 channels
            int pos = t - 196608;
#pragma unroll
            for (int c = 0; c < 8; ++c)
                v[c] = dt ? f2bf(((const float*)vol)[c * 262144 + pos])
                          : ((const u16*)vol)[c * 262144 + pos];
            *(u16x8*)(vol_s + pos * 8) = v;
        } else {                          // lines
            int o = (t - 458752) * 8;
            int l = o >> 12, rr = o & 4095;
            int pos = rr >> 5, c0 = rr & 31;
            const void* src = (l == 0) ? lx : (l == 1) ? ly : lz;
#pragma unroll
            for (int i = 0; i < 8; ++i)
                v[i] = dt ? f2bf(((const float*)src)[(c0 + i) * 128 + pos])
                          : ((const u16*)src)[(c0 + i) * 128 + pos];
            *(u16x8*)(lines_s + o) = v;
        }
    } else if (blk < 1844) {
        int r = (blk - 1798) * 256 + threadIdx.x;   // [0, 11776)
        weights_work(dt, r, Wx, bx, Wy, by, Wz, bz, W1, b1, W2, b2, wbase);
    } else {
        int b = blk - 1844;               // [0, 256)
        for (int i = threadIdx.x; i < NBUCK; i += 256) lh[i] = 0u;
        __syncthreads();
        for (int p = b * 256 + threadIdx.x; p < M; p += HBLOCKS * 256)
            atomicAdd(&lh[make_key(dt, coords, p)], 1u);
        __syncthreads();
        for (int i = threadIdx.x; i < NBUCK; i += 256)
            part[b * NBUCK + i] = (u16)lh[i];
    }
}

// =====================================================================
// fused scan + scatter (cooperative, 256 blocks co-resident):
//   phase 1: wave-parallel column scan — 1024 waves, each scans 4 buckets
//            (part[.][bkt] -> exclusive prefix in place, tot[bkt] = total)
//   grid sync (replaces the separate kp_colscan launch)
//   phase 2: deterministic scatter, LDS counters, packed 16B records.
// =====================================================================
__global__ __launch_bounds__(256) void kp_scan_scatter(
    const void* __restrict__ coords, u16* __restrict__ part,
    unsigned int* __restrict__ tot,
    u32* __restrict__ recs, int M)
{
    __shared__ unsigned int cnt[NBUCK];
    __shared__ unsigned int psum[256];
    int b = blockIdx.x;          // [0, 256)
    int t = threadIdx.x;
    int lane = t & 63;
    int wv   = t >> 6;

    // ---- phase 1: column scan of 16 buckets per block (4 per wave) ----
#pragma unroll 1
    for (int ib = 0; ib < 4; ++ib) {
        int bkt = b * 16 + wv * 4 + ib;
        unsigned int v[4];
        unsigned int ltot = 0;
#pragma unroll
        for (int i = 0; i < 4; ++i) {
            v[i] = part[(lane * 4 + i) * NBUCK + bkt];
            ltot += v[i];
        }
        unsigned int x = ltot;
#pragma unroll
        for (int d = 1; d < 64; d <<= 1) {
            unsigned int y = __shfl_up(x, d);
            if (lane >= d) x += y;
        }
        unsigned int run = x - ltot;   // exclusive prefix
#pragma unroll
        for (int i = 0; i < 4; ++i) {
            part[(lane * 4 + i) * NBUCK + bkt] = (u16)run;
            run += v[i];
        }
        if (lane == 63) tot[bkt] = x;
    }
    __threadfence();
    cooperative_groups::this_grid().sync();

    // ---- phase 2: scatter (reads part/tot written by all blocks) ----
    unsigned int bs[16];
    unsigned int s = 0;
#pragma unroll
    for (int i = 0; i < 16; ++i) {
        bs[i] = tot[t * 16 + i];
        s += bs[i];
    }
    psum[t] = s;
    __syncthreads();
    // inclusive Hillis-Steele scan over psum[256]
#pragma unroll
    for (int d = 1; d < 256; d <<= 1) {
        unsigned int v = (t >= d) ? psum[t - d] : 0u;
        __syncthreads();
        psum[t] += v;
        __syncthreads();
    }
    unsigned int run = psum[t] - s;   // exclusive prefix
#pragma unroll
    for (int i = 0; i < 16; ++i) {
        int bkt = t * 16 + i;
        cnt[bkt] = run + (unsigned int)part[b * NBUCK + bkt];
        run += bs[i];
    }
    __syncthreads();
    int dt = detect_dt(coords);
    const u16* cu = (const u16*)coords;
    for (int p = b * 256 + t; p < M; p += HBLOCKS * 256) {
        float x = gld(dt, coords, p * 3 + 0);
        float y = gld(dt, coords, p * 3 + 1);
        float z = gld(dt, coords, p * 3 + 2);
        int key = make_key3(x, y, z);
        unsigned int pos = atomicAdd(&cnt[key], 1u);
        u32x4 r;
        r.x = (u32)p;
        if (dt == 0) {
            r.y = (u32)cu[p * 3 + 0] | ((u32)cu[p * 3 + 1] << 16);
            r.z = (u32)cu[p * 3 + 2];
        } else {
            r.y = 0u; r.z = 0u;
        }
        r.w = 0u;
        *(u32x4*)(recs + (size_t)pos * 4u) = r;
    }
}

// =====================================================================
// non-cooperative fallbacks (if cooperative launch unavailable)
// =====================================================================
__global__ __launch_bounds__(256) void kp_colscan_fb(
    u16* __restrict__ part, unsigned int* __restrict__ tot)
{
    int lane = threadIdx.x & 63;
    int bkt  = blockIdx.x * 4 + (threadIdx.x >> 6);
    unsigned int v[4];
    unsigned int ltot = 0;
#pragma unroll
    for (int i = 0; i < 4; ++i) {
        v[i] = part[(lane * 4 + i) * NBUCK + bkt];
        ltot += v[i];
    }
    unsigned int x = ltot;
#pragma unroll
    for (int d = 1; d < 64; d <<= 1) {
        unsigned int y = __shfl_up(x, d);
        if (lane >= d) x += y;
    }
    unsigned int run = x - ltot;
#pragma unroll
    for (int i = 0; i < 4; ++i) {
        part[(lane * 4 + i) * NBUCK + bkt] = (u16)run;
        run += v[i];
    }
    if (lane == 63) tot[bkt] = x;
}

__global__ __launch_bounds__(256) void kp_scatter_fb(
    const void* __restrict__ coords, const u16* __restrict__ part,
    const unsigned int* __restrict__ tot,
    u32* __restrict__ recs, int M)
{
    __shared__ unsigned int cnt[NBUCK];
    __shared__ unsigned int psum[256];
    int b = blockIdx.x;
    int t = threadIdx.x;
    unsigned int bs[16];
    unsigned int s = 0;
#pragma unroll
    for (int i = 0; i < 16; ++i) {
        bs[i] = tot[t * 16 + i];
        s += bs[i];
    }
    psum[t] = s;
    __syncthreads();
#pragma unroll
    for (int d = 1; d < 256; d <<= 1) {
        unsigned int v = (t >= d) ? psum[t - d] : 0u;
        __syncthreads();
        psum[t] += v;
        __syncthreads();
    }
    unsigned int run = psum[t] - s;
#pragma unroll
    for (int i = 0; i < 16; ++i) {
        int bkt = t * 16 + i;
        cnt[bkt] = run + (unsigned int)part[b * NBUCK + bkt];
        run += bs[i];
    }
    __syncthreads();
    int dt = detect_dt(coords);
    const u16* cu = (const u16*)coords;
    for (int p = b * 256 + t; p < M; p += HBLOCKS * 256) {
        float x = gld(dt, coords, p * 3 + 0);
        float y = gld(dt, coords, p * 3 + 1);
        float z = gld(dt, coords, p * 3 + 2);
        int key = make_key3(x, y, z);
        unsigned int pos = atomicAdd(&cnt[key], 1u);
        u32x4 r;
        r.x = (u32)p;
        if (dt == 0) {
            r.y = (u32)cu[p * 3 + 0] | ((u32)cu[p * 3 + 1] << 16);
            r.z = (u32)cu[p * 3 + 2];
        } else {
            r.y = 0u; r.z = 0u;
        }
        r.w = 0u;
        *(u32x4*)(recs + (size_t)pos * 4u) = r;
    }
}

// =====================================================================
// shared math
// =====================================================================
struct Samp { int i0, i1; float w0, w1; };

static __device__ __forceinline__ Samp make_samp(float g, int N) {
    float ix = (g + 1.0f) * 0.5f * (float)(N - 1);
    float fl = floorf(ix);
    float w  = ix - fl;
    int i  = (int)fl;
    int i1 = i + 1;
    float v0 = (i  >= 0 && i  < N) ? 1.0f : 0.0f;
    float v1 = (i1 >= 0 && i1 < N) ? 1.0f : 0.0f;
    Samp s;
    s.w0 = (1.0f - w) * v0;
    s.w1 = w * v1;
    s.i0 = min(max(i, 0), N - 1);
    s.i1 = min(max(i1, 0), N - 1);
    return s;
}

#define MFMA16(a, b, c) __builtin_amdgcn_mfma_f32_16x16x32_f16((a), (b), (c), 0, 0, 0)

// LDS strides (halves). SRE=40/SR2=72: row stride 80B keeps the h8v
// LDS ops 16B-aligned (ds_*_b128). R6's SRE=34 (68B) broke alignment and
// regressed 81->88 us despite zero bank conflicts.
#define SRE 40
#define SR2 72

// register-staged plane gathers for ONE term: 16 x 16B (64 VGPR)
struct PL { u16x8 q00[4], q01[4], q10[4], q11[4]; };
struct VL { u16x8 v[8]; };

static __device__ __forceinline__ void plane_load(
    const u16* __restrict__ Ps, const Samp& sa, const Samp& sb, PL& P)
{
    const u16x8* p00 = (const u16x8*)(Ps + (sb.i0 * 128 + sa.i0) * 32);
    const u16x8* p01 = (const u16x8*)(Ps + (sb.i0 * 128 + sa.i1) * 32);
    const u16x8* p10 = (const u16x8*)(Ps + (sb.i1 * 128 + sa.i0) * 32);
    const u16x8* p11 = (const u16x8*)(Ps + (sb.i1 * 128 + sa.i1) * 32);
#pragma unroll
    for (int cc = 0; cc < 4; ++cc) {
        P.q00[cc] = p00[cc]; P.q01[cc] = p01[cc];
        P.q10[cc] = p10[cc]; P.q11[cc] = p11[cc];
    }
}

static __device__ __forceinline__ void vol_loads(
    const u16* __restrict__ vol_s, const Samp& vx, const Samp& vy,
    const Samp& vz, VL& V)
{
#pragma unroll
    for (int corner = 0; corner < 8; ++corner) {
        int dx = corner & 1, dy = (corner >> 1) & 1, dz = corner >> 2;
        int xi = dx ? vx.i1 : vx.i0;
        int yi = dy ? vy.i1 : vy.i0;
        int zi = dz ? vz.i1 : vz.i0;
        V.v[corner] = *(const u16x8*)(vol_s + (((zi * 64) + yi) * 64 + xi) * 8);
    }
}

// One product term (R0 structure) with next-term prefetch issued between
// the conv LDS-writes and the MFMA block, so the next plane/vol gathers'
// latency hides under this term's MFMA + the next term's line-interp.
// PRE: 0 = none, 1 = prefetch plane -> PN, 2 = prefetch volume -> V.
template<int PRE>
static __device__ __forceinline__ void term_step(
    int lane, int q, int l15,
    const u16* __restrict__ Ls, const Samp& sl,
    const PL& P, const Samp& sa, const Samp& sb,
    const _Float16* __restrict__ Wt, const float* __restrict__ bvt,
    _Float16* El, _Float16* Ep, float (&feat)[4][2][4],
    const u16* __restrict__ nps, const Samp& na, const Samp& nb, PL& PN,
    const u16* __restrict__ vol_s, const Samp& vx, const Samp& vy,
    const Samp& vz, VL& V)
{
    const u16x8* l0 = (const u16x8*)(Ls + sl.i0 * 32);
    const u16x8* l1 = (const u16x8*)(Ls + sl.i1 * 32);
    float w00 = sb.w0 * sa.w0, w01 = sb.w0 * sa.w1;
    float w10 = sb.w1 * sa.w0, w11 = sb.w1 * sa.w1;
#pragma unroll
    for (int cc = 0; cc < 4; ++cc) {
        u16x8 A0 = l0[cc], A1 = l1[cc];
        u16x8 Q00 = P.q00[cc], Q01 = P.q01[cc];
        u16x8 Q10 = P.q10[cc], Q11 = P.q11[cc];
        H8 hl, hp;
#pragma unroll
        for (int kk = 0; kk < 4; ++kk) {
            int k0 = 2 * kk, k1 = k0 + 1;
            float el0 = sl.w0 * bf2f(A0[k0]) + sl.w1 * bf2f(A1[k0]);
            float el1 = sl.w0 * bf2f(A0[k1]) + sl.w1 * bf2f(A1[k1]);
            float ep0 = w00 * bf2f(Q00[k0]) + w01 * bf2f(Q01[k0])
                      + w10 * bf2f(Q10[k0]) + w11 * bf2f(Q11[k0]);
            float ep1 = w00 * bf2f(Q00[k1]) + w01 * bf2f(Q01[k1])
                      + w10 * bf2f(Q10[k1]) + w11 * bf2f(Q11[k1]);
            hl.p[kk] = pk(fmaxf(el0, 0.0f), fmaxf(el1, 0.0f));
            hp.p[kk] = pk(fmaxf(ep0, 0.0f), fmaxf(ep1, 0.0f));
        }
        *(h8v*)&El[lane * SRE + cc * 8] = hl.v;
        *(h8v*)&Ep[lane * SRE + cc * 8] = hp.v;
    }
    // prefetch for the NEXT phase: issued before this term's MFMA, consumed
    // after it — latency hidden. lgkm-only fences keep these in flight.
    if constexpr (PRE == 1) plane_load(nps, na, nb, PN);
    if constexpr (PRE == 2) vol_loads(vol_s, vx, vy, vz, V);

    h8v bf0 = *(const h8v*)&Wt[(l15) * 32 + q * 8];
    h8v bf1 = *(const h8v*)&Wt[(16 + l15) * 32 + q * 8];
    float bb0 = bvt[l15], bb1 = bvt[16 + l15];
    f4v c0 = {bb0, bb0, bb0, bb0};
    f4v c1 = {bb1, bb1, bb1, bb1};
    lds_wait();
#pragma unroll
    for (int mt = 0; mt < 4; ++mt) {
        h8v aL = *(const h8v*)&El[(mt * 16 + l15) * SRE + q * 8];
        h8v aP = *(const h8v*)&Ep[(mt * 16 + l15) * SRE + q * 8];
        f4v ta0 = MFMA16(aL, bf0, c0);
        f4v tb0 = MFMA16(aP, bf0, c0);
        f4v ta1 = MFMA16(aL, bf1, c1);
        f4v tb1 = MFMA16(aP, bf1, c1);
#pragma unroll
        for (int r = 0; r < 4; ++r) {
            feat[mt][0][r] += ta0[r] * tb0[r];
            feat[mt][1][r] += ta1[r] * tb1[r];
        }
    }
    lds_wait();   // MFMA operand ds_reads retired before next term overwrites
}

// =====================================================================
// MFMA main — R5 structure (single-wave blocks, El/Ep separate buffers,
// one-term-ahead plane prefetch, lgkm-only fences, SRE=40/SR2=72).
// Point identity + coords come from ONE coalesced 16B record load.
// NOTE: plain __launch_bounds__(64) — a min-waves hint makes the
// allocator clamp VGPRs (R3: clamped to 64 -> 155 MB scratch spills).
// =====================================================================
__global__ __launch_bounds__(64) void kp_main_mfma(
    const void* __restrict__ coords, const u32* __restrict__ recs,
    const u16* __restrict__ planes_s, const u16* __restrict__ vol_s,
    const u16* __restrict__ lines_s,
    const float* __restrict__ wbase,
    void* __restrict__ out, int M)
{
    __shared__ _Float16 eb[5120];   // El[64*40] | Ep[64*40]; reused as E2[64*72]
    __shared__ float res[64];
    int dt = detect_dt(coords);
    const _Float16* WtH = (const _Float16*)wbase;
    const float*    bv  = wbase + 1536;
    const _Float16* W1H = (const _Float16*)(wbase + 1632);
    const float*    b1v = wbase + 5728;
    const float*    W2v = wbase + 5856;
    const float*    b2v = wbase + 5984;

    int lane = threadIdx.x;
    int q = lane >> 4, l15 = lane & 15;
    _Float16* El = eb;
    _Float16* Ep = eb + 2560;
    _Float16* E2 = eb;

    int p = blockIdx.x * 64 + lane;
    p = min(p, M - 1);
    u32x4 rv = *(const u32x4*)(recs + (size_t)p * 4u);
    int sp = (int)rv.x;

    float x, y, z;
    if (dt == 0) {
        x = bf2f((u16)(rv.y & 0xffffu));
        y = bf2f((u16)(rv.y >> 16));
        z = bf2f((u16)(rv.z & 0xffffu));
    } else {
        x = ((const float*)coords)[sp * 3 + 0];
        y = ((const float*)coords)[sp * 3 + 1];
        z = ((const float*)coords)[sp * 3 + 2];
    }

    Samp sx = make_samp(x, 128), sy = make_samp(y, 128), sz = make_samp(z, 128);

    float feat[4][2][4];
#pragma unroll
    for (int mt = 0; mt < 4; ++mt)
#pragma unroll
        for (int n = 0; n < 2; ++n)
#pragma unroll
            for (int r = 0; r < 4; ++r) feat[mt][n][r] = 0.0f;

    PL Pa, Pb;
    VL V;
    Samp vx, vy, vz;   // computed just before term 2 (keeps peak regs low)

    plane_load(planes_s + 1 * 524288, sy, sz, Pa);   // term0 plane (exposed)

    // term 0: line x, plane yz (Pa); prefetch term1 plane xz -> Pb
    term_step<1>(lane, q, l15, lines_s + 0 * 4096, sx, Pa, sy, sz,
                 WtH + 0, bv + 0, El, Ep, feat,
                 planes_s + 2 * 524288, sx, sz, Pb,
                 vol_s, sx, sx, sx, V);

    // term 1: line y, plane xz (Pb); prefetch term2 plane xy -> Pa
    term_step<1>(lane, q, l15, lines_s + 1 * 4096, sy, Pb, sx, sz,
                 WtH + 1024, bv + 32, El, Ep, feat,
                 planes_s + 0 * 524288, sx, sy, Pa,
                 vol_s, sx, sx, sx, V);

    vx = make_samp(x, 64); vy = make_samp(y, 64); vz = make_samp(z, 64);

    // term 2: line z, plane xy (Pa); prefetch volume corners -> V
    term_step<2>(lane, q, l15, lines_s + 2 * 4096, sz, Pa, sx, sy,
                 WtH + 2048, bv + 64, El, Ep, feat,
                 planes_s, sx, sy, Pb,
                 vol_s, vx, vy, vz, V);

    // ---- E2 assembly (feat + trilinear volume from V regs) ----
#pragma unroll
    for (int mt = 0; mt < 4; ++mt)
#pragma unroll
        for (int n = 0; n < 2; ++n)
#pragma unroll
            for (int r = 0; r < 4; ++r)
                E2[(mt * 16 + q * 4 + r) * SR2 + n * 16 + l15] =
                    (_Float16)feat[mt][n][r];
    {
        float vf[8];
#pragma unroll
        for (int c = 0; c < 8; ++c) vf[c] = 0.0f;
#pragma unroll
        for (int corner = 0; corner < 8; ++corner) {
            int dx = corner & 1, dy = (corner >> 1) & 1, dz = corner >> 2;
            float w = (dx ? vx.w1 : vx.w0) * (dy ? vy.w1 : vy.w0)
                    * (dz ? vz.w1 : vz.w0);
            u16x8 v = V.v[corner];
#pragma unroll
            for (int c = 0; c < 8; ++c)
                vf[c] = fmaf(w, bf2f(v[c]), vf[c]);
        }
        H8 hv;
#pragma unroll
        for (int k = 0; k < 4; ++k) hv.p[k] = pk(vf[2 * k], vf[2 * k + 1]);
        *(h8v*)&E2[lane * SR2 + 32] = hv.v;
        h8v zz = {};
        *(h8v*)&E2[lane * SR2 + 40] = zz;
        *(h8v*)&E2[lane * SR2 + 48] = zz;
        *(h8v*)&E2[lane * SR2 + 56] = zz;
    }
    lds_wait();

    h8v af[4][2];
#pragma unroll
    for (int mt = 0; mt < 4; ++mt)
#pragma unroll
        for (int ks = 0; ks < 2; ++ks)
            af[mt][ks] = *(const h8v*)&E2[(mt * 16 + l15) * SR2 + ks * 32 + q * 8];

    float s[4][4];
#pragma unroll
    for (int mt = 0; mt < 4; ++mt)
#pragma unroll
        for (int r = 0; r < 4; ++r) s[mt][r] = 0.0f;

#pragma unroll
    for (int NT = 0; NT < 8; ++NT) {
        int o = NT * 16 + l15;
        h8v b0  = *(const h8v*)&W1H[o * 64 + q * 8];
        h8v b1f = *(const h8v*)&W1H[o * 64 + 32 + q * 8];
        float w2 = W2v[o];
        float bb = b1v[o];
        f4v cinit = {bb, bb, bb, bb};
#pragma unroll
        for (int mt = 0; mt < 4; ++mt) {
            f4v c = MFMA16(af[mt][0], b0, cinit);
            c = MFMA16(af[mt][1], b1f, c);
#pragma unroll
            for (int r = 0; r < 4; ++r)
                s[mt][r] = fmaf(fmaxf(c[r], 0.0f), w2, s[mt][r]);
        }
    }
#pragma unroll
    for (int mt = 0; mt < 4; ++mt)
#pragma unroll
        for (int r = 0; r < 4; ++r) {
            float v = s[mt][r];
            v += __shfl_xor(v, 1);
            v += __shfl_xor(v, 2);
            v += __shfl_xor(v, 4);
            v += __shfl_xor(v, 8);
            s[mt][r] = v;
        }
    if (l15 == 0) {
#pragma unroll
        for (int mt = 0; mt < 4; ++mt)
#pragma unroll
            for (int r = 0; r < 4; ++r)
                res[mt * 16 + q * 4 + r] = s[mt][r];
    }
    lds_wait();
    float rr = res[lane] + b2v[0];
    if (dt) ((float*)out)[sp] = rr;
    else    ((u16*)out)[sp] = f2bf(rr);
}

// =====================================================================
// fallback path (ws too small): weights-only prep + direct gathers
// =====================================================================
__global__ void kp_prep_weights_fb(
    const void* __restrict__ coords,
    const void* __restrict__ Wx, const void* __restrict__ bx,
    const void* __restrict__ Wy, const void* __restrict__ by,
    const void* __restrict__ Wz, const void* __restrict__ bz,
    const void* __restrict__ W1, const void* __restrict__ b1,
    const void* __restrict__ W2, const void* __restrict__ b2,
    float* __restrict__ wbase)
{
    int dt = detect_dt(coords);
    int t = blockIdx.x * blockDim.x + threadIdx.x;
    weights_work(dt, t, Wx, bx, Wy, by, Wz, bz, W1, b1, W2, b2, wbase);
}

__global__ __launch_bounds__(256) void kp_main_direct(
    const void* __restrict__ coords,
    const void* __restrict__ lx, const void* __restrict__ ly, const void* __restrict__ lz,
    const void* __restrict__ pxy, const void* __restrict__ pyz, const void* __restrict__ pxz,
    const void* __restrict__ vol,
    const float* __restrict__ wbase,
    void* __restrict__ out, int M)
{
    int dt = detect_dt(coords);
    const _Float16* WtH = (const _Float16*)wbase;
    const float*    bv  = wbase + 1536;
    const _Float16* W1H = (const _Float16*)(wbase + 1632);
    const float*    b1v = wbase + 5728;
    const float*    W2v = wbase + 5856;
    const float*    b2v = wbase + 5984;

    int p = blockIdx.x * 256 + threadIdx.x;
    p = min(p, M - 1);

    float x = gld(dt, coords, p * 3 + 0);
    float y = gld(dt, coords, p * 3 + 1);
    float z = gld(dt, coords, p * 3 + 2);

    Samp sx = make_samp(x, 128), sy = make_samp(y, 128), sz = make_samp(z, 128);

    float feat[40];
#pragma unroll
    for (int o = 0; o < 40; ++o) feat[o] = 0.0f;

    const void* Ls[3] = {lx, ly, lz};
    const void* Psv[3] = {pyz, pxz, pxy};
    Samp sl3[3] = {sx, sy, sz};
    Samp sa3[3] = {sy, sx, sx};
    Samp sb3[3] = {sz, sz, sy};
#pragma unroll 1
    for (int m = 0; m < 3; ++m) {
        float ta[32], tb[32];
        const float* bvt = bv + m * 32;
        const _Float16* Wt = WtH + m * 1024;
#pragma unroll
        for (int o = 0; o < 32; ++o) { ta[o] = bvt[o]; tb[o] = bvt[o]; }
        Samp sl = sl3[m], sa = sa3[m], sb = sb3[m];
        float w00 = sb.w0 * sa.w0, w01 = sb.w0 * sa.w1;
        float w10 = sb.w1 * sa.w0, w11 = sb.w1 * sa.w1;
        int i00 = sb.i0 * 128 + sa.i0, i01 = sb.i0 * 128 + sa.i1;
        int i10 = sb.i1 * 128 + sa.i0, i11 = sb.i1 * 128 + sa.i1;
#pragma unroll 1
        for (int c = 0; c < 32; ++c) {
            float el = sl.w0 * gld(dt, Ls[m], c * 128 + sl.i0)
                     + sl.w1 * gld(dt, Ls[m], c * 128 + sl.i1);
            float ep = w00 * gld(dt, Psv[m], c * 16384 + i00)
                     + w01 * gld(dt, Psv[m], c * 16384 + i01)
                     + w10 * gld(dt, Psv[m], c * 16384 + i10)
                     + w11 * gld(dt, Psv[m], c * 16384 + i11);
            float r1 = fmaxf(el, 0.0f), r2 = fmaxf(ep, 0.0f);
#pragma unroll
            for (int o = 0; o < 32; ++o) {
                float w = (float)Wt[o * 32 + c];
                ta[o] = fmaf(r1, w, ta[o]);
                tb[o] = fmaf(r2, w, tb[o]);
            }
        }
#pragma unroll
        for (int o = 0; o < 32; ++o) feat[o] = fmaf(ta[o], tb[o], feat[o]);
    }

    Samp vx = make_samp(x, 64), vy = make_samp(y, 64), vz = make_samp(z, 64);
#pragma unroll 1
    for (int corner = 0; corner < 8; ++corner) {
        int dx = corner & 1, dy = (corner >> 1) & 1, dz = corner >> 2;
        int xi = dx ? vx.i1 : vx.i0;
        int yi = dy ? vy.i1 : vy.i0;
        int zi = dz ? vz.i1 : vz.i0;
        float w = (dx ? vx.w1 : vx.w0) * (dy ? vy.w1 : vy.w0) * (dz ? vz.w1 : vz.w0);
        int pos = ((zi * 64) + yi) * 64 + xi;
#pragma unroll
        for (int c = 0; c < 8; ++c)
            feat[32 + c] = fmaf(w, gld(dt, vol, c * 262144 + pos), feat[32 + c]);
    }

    float acc_out = b2v[0];
#pragma unroll 2
    for (int j = 0; j < 128; ++j) {
        float acc = b1v[j];
        const _Float16* wr = W1H + j * 64;
#pragma unroll
        for (int i = 0; i < 40; ++i)
            acc = fmaf(feat[i], (float)wr[i], acc);
        acc_out = fmaf(fmaxf(acc, 0.0f), W2v[j], acc_out);
    }
    if (dt) ((float*)out)[p] = acc_out;
    else    ((u16*)out)[p] = f2bf(acc_out);
}

// =====================================================================
extern "C" void kernel_launch(void* const* d_in, const int* in_sizes, int n_in,
                              void* d_out, int out_size, void* d_ws, size_t ws_size,
                              hipStream_t stream) {
    const void* coords = d_in[0];
    const void* lx  = d_in[1];
    const void* ly  = d_in[2];
    const void* lz  = d_in[3];
    const void* pxy = d_in[4];
    const void* pyz = d_in[5];
    const void* pxz = d_in[6];
    const void* vol = d_in[7];
    const void* Wx  = d_in[8];
    const void* bx  = d_in[9];
    const void* Wy  = d_in[10];
    const void* by  = d_in[11];
    const void* Wz  = d_in[12];
    const void* bz  = d_in[13];
    const void* W1  = d_in[14];
    const void* b1  = d_in[15];
    const void* W2  = d_in[16];
    const void* b2  = d_in[17];

    int M = in_sizes[0] / 3;

    char* ws = (char*)d_ws;
    float*        wbase    = (float*)(ws + WF_OFF);
    u16*          planes_s = (u16*)(ws + PLANES_S_OFF);
    u16*          vol_s    = (u16*)(ws + VOL_S_OFF);
    u16*          lines_s  = (u16*)(ws + LINES_S_OFF);
    u16*          part     = (u16*)(ws + PART_OFF);
    unsigned int* tot      = (unsigned int*)(ws + TOT_OFF);
    u32*          recs     = (u32*)(ws + REC_OFF);

    size_t need_sorted = (size_t)REC_OFF + (size_t)M * 16u;

    if (ws_size >= need_sorted) {
        kp_prep_all<<<2100, 256, 0, stream>>>(coords, lx, ly, lz, pxy, pyz, pxz, vol,
                                              Wx, bx, Wy, by, Wz, bz, W1, b1, W2, b2,
                                              wbase, planes_s, vol_s, lines_s, part, M);
        // fused scan+scatter (cooperative grid sync replaces a launch)
        {
            void* cvd = (void*)coords;
            void* args[] = {(void*)&cvd, (void*)&part, (void*)&tot,
                            (void*)&recs, (void*)&M};
            hipError_t e = hipLaunchCooperativeKernel(
                (const void*)kp_scan_scatter, dim3(HBLOCKS), dim3(256),
                args, 0, stream);
            if (e != hipSuccess) {   // fallback: two plain launches
                kp_colscan_fb<<<NBUCK / 4, 256, 0, stream>>>(part, tot);
                kp_scatter_fb<<<HBLOCKS, 256, 0, stream>>>(coords, part, tot,
                                                           recs, M);
            }
        }
        int blocks64 = (M + 63) / 64;
        kp_main_mfma<<<blocks64, 64, 0, stream>>>(coords, recs,
                                                  planes_s, vol_s, lines_s,
                                                  wbase, d_out, M);
    } else {
        int blocks = (M + 255) / 256;
        kp_prep_weights_fb<<<46, 256, 0, stream>>>(coords, Wx, bx, Wy, by, Wz, bz,
                                                   W1, b1, W2, b2, wbase);
        kp_main_direct<<<blocks, 256, 0, stream>>>(coords, lx, ly, lz, pxy, pyz, pxz,
                                                   vol, wbase, d_out, M);
    }
}

// Round 10
// 202.186 us; speedup vs baseline: 1.5433x; 1.5433x over previous
//
#include <hip/hip_runtime.h>

typedef unsigned short u16;
typedef u16 u16x8 __attribute__((ext_vector_type(8)));
typedef _Float16 half2 __attribute__((ext_vector_type(2)));
typedef _Float16 h8v __attribute__((ext_vector_type(8)));
typedef float f4v __attribute__((ext_vector_type(4)));

union H8 { h8v v; half2 p[4]; };

// ---------- bf16 helpers ----------
static __device__ __forceinline__ float bf2f(u16 u) {
    union { unsigned int i; float f; } v;
    v.i = ((unsigned int)u) << 16;
    return v.f;
}
static __device__ __forceinline__ u16 f2bf(float f) {
    union { float f; unsigned int i; } v;
    v.f = f;
    unsigned int x = v.i;
    x += 0x7fffu + ((x >> 16) & 1u);   // RNE
    return (u16)(x >> 16);
}
static __device__ __forceinline__ float gld(int dt, const void* p, int i) {
    return dt ? ((const float*)p)[i] : bf2f(((const u16*)p)[i]);
}
static __device__ __forceinline__ int detect_dt(const void* coords) {
    u16 v = ((const u16*)coords)[threadIdx.x & 63];
    int e = (v >> 7) & 0xFF;
    bool inr = (e >= 90) && (e <= 126);
    unsigned long long m = __ballot(inr);
    return (__popcll(m) >= 56) ? 0 : 1;   // 0=bf16, 1=f32
}
static __device__ __forceinline__ half2 pk(float a, float b) {
    return __builtin_bit_cast(half2, __builtin_amdgcn_cvt_pkrtz(a, b));
}

// Per-wave LDS ordering (each wave owns a disjoint LDS slice): waits own
// wave's DS ops WITHOUT draining vmcnt, so global gathers stay in flight.
static __device__ __forceinline__ void lds_wait() {
    asm volatile("s_waitcnt lgkmcnt(0)" ::: "memory");
}

// ---------- ws layout (bytes) ----------
#define WF_OFF        64u
#define PLANES_S_OFF  34304u         // 3*524288 u16
#define VOL_S_OFF     3180032u       // 2097152 u16
#define LINES_S_OFF   7374336u       // 12288 u16
#define PART_OFF      7398912u       // 256*4096 u16 = 2 MB
#define TOT_OFF       9496064u       // 4096 u32
#define ORDER_OFF     9512448u       // 4*M
// SCOORD_OFF = ORDER_OFF + 4*M (runtime), 6*M bytes (u16 x3)

#define NBUCK 4096
#define HBLOCKS 256

// =====================================================================
// spatial key
// =====================================================================
static __device__ __forceinline__ int make_key3(float x, float y, float z) {
    int kx = min(max((int)((x + 1.0f) * 8.0f), 0), 15);
    int ky = min(max((int)((y + 1.0f) * 8.0f), 0), 15);
    int kz = min(max((int)((z + 1.0f) * 8.0f), 0), 15);
    return (kz * 16 + ky) * 16 + kx;
}
static __device__ __forceinline__ int make_key(int dt, const void* coords, int p) {
    return make_key3(gld(dt, coords, p * 3 + 0), gld(dt, coords, p * 3 + 1),
                     gld(dt, coords, p * 3 + 2));
}

// =====================================================================
// weight packing (f16 MFMA layouts)
// =====================================================================
static __device__ __forceinline__ void weights_work(
    int dt, int r,
    const void* Wx, const void* bx, const void* Wy, const void* by,
    const void* Wz, const void* bz, const void* W1, const void* b1,
    const void* W2, const void* b2, float* wbase)
{
    _Float16* WtH = (_Float16*)wbase;
    float*    bv  = wbase + 1536;
    _Float16* W1H = (_Float16*)(wbase + 1632);
    float*    b1v = wbase + 5728;
    float*    W2v = wbase + 5856;
    float*    b2v = wbase + 5984;
    if (r < 3072) {
        int m = r >> 10, idx = r & 1023;
        int o = idx >> 5, c = idx & 31;
        const void* s = (m == 0) ? Wx : (m == 1) ? Wy : Wz;
        WtH[r] = (_Float16)gld(dt, s, c * 32 + o);   // Wt[m][o][c] = W[c][o]
    } else if (r < 3168) {
        int q2 = r - 3072;
        int m = q2 >> 5, c = q2 & 31;
        const void* s = (m == 0) ? bx : (m == 1) ? by : bz;
        bv[q2] = gld(dt, s, c);
    } else if (r < 11360) {
        int idx = r - 3168;                 // j*64 + i
        int j = idx >> 6, i = idx & 63;
        W1H[idx] = (i < 40) ? (_Float16)gld(dt, W1, i * 128 + j) : (_Float16)0.0f;
    } else if (r < 11488) {
        b1v[r - 11360] = gld(dt, b1, r - 11360);
    } else if (r < 11616) {
        W2v[r - 11488] = gld(dt, W2, r - 11488);
    } else if (r == 11616) {
        b2v[0] = gld(dt, b2, 0);
    }
}

// =====================================================================
// fused prep: grid transpose (0..1797) + weights (1798..1843)
//           + histogram partials u16, plain stores (1844..2099)
// =====================================================================
__global__ __launch_bounds__(256) void kp_prep_all(
    const void* __restrict__ coords,
    const void* __restrict__ lx, const void* __restrict__ ly,
    const void* __restrict__ lz,
    const void* __restrict__ pxy, const void* __restrict__ pyz,
    const void* __restrict__ pxz, const void* __restrict__ vol,
    const void* __restrict__ Wx, const void* __restrict__ bx,
    const void* __restrict__ Wy, const void* __restrict__ by,
    const void* __restrict__ Wz, const void* __restrict__ bz,
    const void* __restrict__ W1, const void* __restrict__ b1,
    const void* __restrict__ W2, const void* __restrict__ b2,
    float* __restrict__ wbase,
    u16* __restrict__ planes_s, u16* __restrict__ vol_s,
    u16* __restrict__ lines_s, u16* __restrict__ part, int M)
{
    __shared__ unsigned int lh[NBUCK];
    int dt = detect_dt(coords);
    int blk = blockIdx.x;
    if (blk < 1798) {
        int t = blk * 256 + threadIdx.x;   // [0, 460288)
        u16x8 v;
        if (t < 196608) {                 // planes: 8 consecutive out u16
            int o = t * 8;
            int pl = o >> 19;
            int r  = o & 524287;
            int pos = r >> 5, c0 = r & 31;
            const void* src = (pl == 0) ? pxy : (pl == 1) ? pyz : pxz;
#pragma unroll
            for (int i = 0; i < 8; ++i)
                v[i] = dt ? f2bf(((const float*)src)[(c0 + i) * 16384 + pos])
                          : ((const u16*)src)[(c0 + i) * 16384 + pos];
            *(u16x8*)(planes_s + o) = v;
        } else if (t < 458752) {          // volume: thread = one pos, 8 channels
            int pos = t - 196608;
#pragma unroll
            for (int c = 0; c < 8; ++c)
                v[c] = dt ? f2bf(((const float*)vol)[c * 262144 + pos])
                          : ((const u16*)vol)[c * 262144 + pos];
            *(u16x8*)(vol_s + pos * 8) = v;
        } else {                          // lines
            int o = (t - 458752) * 8;
            int l = o >> 12, rr = o & 4095;
            int pos = rr >> 5, c0 = rr & 31;
            const void* src = (l == 0) ? lx : (l == 1) ? ly : lz;
#pragma unroll
            for (int i = 0; i < 8; ++i)
                v[i] = dt ? f2bf(((const float*)src)[(c0 + i) * 128 + pos])
                          : ((const u16*)src)[(c0 + i) * 128 + pos];
            *(u16x8*)(lines_s + o) = v;
        }
    } else if (blk < 1844) {
        int r = (blk - 1798) * 256 + threadIdx.x;   // [0, 11776)
        weights_work(dt, r, Wx, bx, Wy, by, Wz, bz, W1, b1, W2, b2, wbase);
    } else {
        int b = blk - 1844;               // [0, 256)
        for (int i = threadIdx.x; i < NBUCK; i += 256) lh[i] = 0u;
        __syncthreads();
        for (int p = b * 256 + threadIdx.x; p < M; p += HBLOCKS * 256)
            atomicAdd(&lh[make_key(dt, coords, p)], 1u);
        __syncthreads();
        for (int i = threadIdx.x; i < NBUCK; i += 256)
            part[b * NBUCK + i] = (u16)lh[i];
    }
}

// =====================================================================
// column scan: part[b][bkt] (u16) -> exclusive prefix over b (in place),
// tot[bkt] = column total.  (R5 configuration — best measured e2e.)
// =====================================================================
__global__ __launch_bounds__(64) void kp_colscan(
    u16* __restrict__ part, unsigned int* __restrict__ tot)
{
    int bkt = blockIdx.x * 64 + threadIdx.x;   // 64 blocks x 64
    unsigned int run = 0;
#pragma unroll 8
    for (int k = 0; k < HBLOCKS; ++k) {
        unsigned int v = part[k * NBUCK + bkt];
        part[k * NBUCK + bkt] = (u16)run;
        run += v;
    }
    tot[bkt] = run;
}

// =====================================================================
// deterministic scatter: 256 blocks, LDS counters, no global atomics.
// Also emits reordered raw-bf16 coords (dt==0) for coalesced main reads.
// =====================================================================
__global__ __launch_bounds__(256) void kp_scatter_det(
    const void* __restrict__ coords, const u16* __restrict__ part,
    const unsigned int* __restrict__ tot,
    int* __restrict__ order, u16* __restrict__ scoords, int M)
{
    __shared__ unsigned int cnt[NBUCK];
    __shared__ unsigned int psum[256];
    int b = blockIdx.x;          // [0, 256)
    int t = threadIdx.x;
    unsigned int bs[16];
    unsigned int s = 0;
#pragma unroll
    for (int i = 0; i < 16; ++i) {
        bs[i] = tot[t * 16 + i];
        s += bs[i];
    }
    psum[t] = s;
    __syncthreads();
    if (t == 0) {
        unsigned int run = 0;
        for (int i = 0; i < 256; ++i) { unsigned int v = psum[i]; psum[i] = run; run += v; }
    }
    __syncthreads();
    unsigned int run = psum[t];
#pragma unroll
    for (int i = 0; i < 16; ++i) {
        int bkt = t * 16 + i;
        cnt[bkt] = run + (unsigned int)part[b * NBUCK + bkt];
        run += bs[i];
    }
    __syncthreads();
    int dt = detect_dt(coords);
    const u16* cu = (const u16*)coords;
    for (int p = b * 256 + t; p < M; p += HBLOCKS * 256) {
        float x = gld(dt, coords, p * 3 + 0);
        float y = gld(dt, coords, p * 3 + 1);
        float z = gld(dt, coords, p * 3 + 2);
        int key = make_key3(x, y, z);
        unsigned int pos = atomicAdd(&cnt[key], 1u);
        order[pos] = p;
        if (dt == 0) {
            scoords[pos * 3 + 0] = cu[p * 3 + 0];
            scoords[pos * 3 + 1] = cu[p * 3 + 1];
            scoords[pos * 3 + 2] = cu[p * 3 + 2];
        }
    }
}

// =====================================================================
// shared math
// =====================================================================
struct Samp { int i0, i1; float w0, w1; };

static __device__ __forceinline__ Samp make_samp(float g, int N) {
    float ix = (g + 1.0f) * 0.5f * (float)(N - 1);
    float fl = floorf(ix);
    float w  = ix - fl;
    int i  = (int)fl;
    int i1 = i + 1;
    float v0 = (i  >= 0 && i  < N) ? 1.0f : 0.0f;
    float v1 = (i1 >= 0 && i1 < N) ? 1.0f : 0.0f;
    Samp s;
    s.w0 = (1.0f - w) * v0;
    s.w1 = w * v1;
    s.i0 = min(max(i, 0), N - 1);
    s.i1 = min(max(i1, 0), N - 1);
    return s;
}

#define MFMA16(a, b, c) __builtin_amdgcn_mfma_f32_16x16x32_f16((a), (b), (c), 0, 0, 0)

// per-wave shared buffer stride (halves): 64 rows x 40 (80B rows, b128 ok)
#define SB 40

// one product term, two-phase through this wave's SINGLE shared buffer:
//   A: line-E -> buf -> MFMA -> ta regs;  B: plane-E -> buf -> MFMA tb,
//   feat += ta*tb.  LDS ordering is lgkm-only (vmem stays in flight).
// (R4-proven structure.)
static __device__ __forceinline__ void term_phase(
    int lane, int q, int l15,
    const u16* __restrict__ Ls, const Samp& sl,
    const u16* __restrict__ Ps, const Samp& sa, const Samp& sb,
    const _Float16* __restrict__ Wt, const float* __restrict__ bvt,
    _Float16* buf, float (&feat)[4][2][4])
{
    const u16x8* l0  = (const u16x8*)(Ls + sl.i0 * 32);
    const u16x8* l1  = (const u16x8*)(Ls + sl.i1 * 32);
    const u16x8* p00 = (const u16x8*)(Ps + (sb.i0 * 128 + sa.i0) * 32);
    const u16x8* p01 = (const u16x8*)(Ps + (sb.i0 * 128 + sa.i1) * 32);
    const u16x8* p10 = (const u16x8*)(Ps + (sb.i1 * 128 + sa.i0) * 32);
    const u16x8* p11 = (const u16x8*)(Ps + (sb.i1 * 128 + sa.i1) * 32);
    float w00 = sb.w0 * sa.w0, w01 = sb.w0 * sa.w1;
    float w10 = sb.w1 * sa.w0, w11 = sb.w1 * sa.w1;

    // ---- phase A: line interp -> buf ----
#pragma unroll
    for (int cc = 0; cc < 4; ++cc) {
        u16x8 A0 = l0[cc], A1 = l1[cc];
        H8 hl;
#pragma unroll
        for (int kk = 0; kk < 4; ++kk) {
            int k0 = 2 * kk, k1 = k0 + 1;
            float e0 = sl.w0 * bf2f(A0[k0]) + sl.w1 * bf2f(A1[k0]);
            float e1 = sl.w0 * bf2f(A0[k1]) + sl.w1 * bf2f(A1[k1]);
            hl.p[kk] = pk(fmaxf(e0, 0.0f), fmaxf(e1, 0.0f));
        }
        *(h8v*)&buf[lane * SB + cc * 8] = hl.v;
    }
    h8v bf0 = *(const h8v*)&Wt[l15 * 32 + q * 8];
    h8v bf1 = *(const h8v*)&Wt[(16 + l15) * 32 + q * 8];
    float bb0 = bvt[l15], bb1 = bvt[16 + l15];
    f4v c0 = {bb0, bb0, bb0, bb0};
    f4v c1 = {bb1, bb1, bb1, bb1};
    lds_wait();
    f4v ta0[4], ta1[4];
#pragma unroll
    for (int mt = 0; mt < 4; ++mt) {
        h8v aL = *(const h8v*)&buf[(mt * 16 + l15) * SB + q * 8];
        ta0[mt] = MFMA16(aL, bf0, c0);
        ta1[mt] = MFMA16(aL, bf1, c1);
    }
    lds_wait();   // aL reads retired before phase B overwrites buf

    // ---- phase B: plane interp -> buf -> tb, feat += ta*tb ----
#pragma unroll
    for (int cc = 0; cc < 4; ++cc) {
        u16x8 Q00 = p00[cc], Q01 = p01[cc], Q10 = p10[cc], Q11 = p11[cc];
        H8 hp;
#pragma unroll
        for (int kk = 0; kk < 4; ++kk) {
            int k0 = 2 * kk, k1 = k0 + 1;
            float e0 = w00 * bf2f(Q00[k0]) + w01 * bf2f(Q01[k0])
                     + w10 * bf2f(Q10[k0]) + w11 * bf2f(Q11[k0]);
            float e1 = w00 * bf2f(Q00[k1]) + w01 * bf2f(Q01[k1])
                     + w10 * bf2f(Q10[k1]) + w11 * bf2f(Q11[k1]);
            hp.p[kk] = pk(fmaxf(e0, 0.0f), fmaxf(e1, 0.0f));
        }
        *(h8v*)&buf[lane * SB + cc * 8] = hp.v;
    }
    lds_wait();
#pragma unroll
    for (int mt = 0; mt < 4; ++mt) {
        h8v aP = *(const h8v*)&buf[(mt * 16 + l15) * SB + q * 8];
        f4v tb0 = MFMA16(aP, bf0, c0);
        f4v tb1 = MFMA16(aP, bf1, c1);
#pragma unroll
        for (int r = 0; r < 4; ++r) {
            feat[mt][0][r] += ta0[mt][r] * tb0[r];
            feat[mt][1][r] += ta1[mt][r] * tb1[r];
        }
    }
    lds_wait();   // aP reads retired before next phase overwrites buf
}

struct VL { u16x8 v[8]; };

static __device__ __forceinline__ void vol_loads(
    const u16* __restrict__ vol_s, const Samp& vx, const Samp& vy,
    const Samp& vz, VL& V)
{
#pragma unroll
    for (int corner = 0; corner < 8; ++corner) {
        int dx = corner & 1, dy = (corner >> 1) & 1, dz = corner >> 2;
        int xi = dx ? vx.i1 : vx.i0;
        int yi = dy ? vy.i1 : vy.i0;
        int zi = dz ? vz.i1 : vz.i0;
        V.v[corner] = *(const u16x8*)(vol_s + (((zi * 64) + yi) * 64 + xi) * 8);
    }
}

// =====================================================================
// MFMA main — 2-WAVE blocks (128 threads), each wave a private 5.1KB
// single-buffer slice (R4-proven 4-phase scheme). Tests the wg-slot
// occupancy hypothesis: 10.75KB/wg -> 6 wg/CU -> 12 waves/CU if the
// prior ~6.4-wave pin was a per-CU workgroup-slot limit on 1-wave wgs.
// Plain __launch_bounds__(128): NO min-waves hint (R3: clamp -> spills).
// =====================================================================
__global__ __launch_bounds__(128) void kp_main_mfma(
    const void* __restrict__ coords, const int* __restrict__ order,
    const u16* __restrict__ scoords,
    const u16* __restrict__ planes_s, const u16* __restrict__ vol_s,
    const u16* __restrict__ lines_s,
    const float* __restrict__ wbase,
    void* __restrict__ out, int M)
{
    __shared__ _Float16 buf[2][64 * SB];   // per-wave 5120 B
    __shared__ float res[2][64];
    int dt = detect_dt(coords);
    const _Float16* WtH = (const _Float16*)wbase;
    const float*    bv  = wbase + 1536;
    const _Float16* W1H = (const _Float16*)(wbase + 1632);
    const float*    b1v = wbase + 5728;
    const float*    W2v = wbase + 5856;
    const float*    b2v = wbase + 5984;

    int tid  = threadIdx.x;
    int wv   = tid >> 6;
    int lane = tid & 63;
    int q = lane >> 4, l15 = lane & 15;
    _Float16* bw   = buf[wv];
    float*    resw = res[wv];

    int p = blockIdx.x * 128 + tid;
    p = min(p, M - 1);
    int sp = order[p];

    float x, y, z;
    if (dt == 0) {
        x = bf2f(scoords[p * 3 + 0]);
        y = bf2f(scoords[p * 3 + 1]);
        z = bf2f(scoords[p * 3 + 2]);
    } else {
        x = ((const float*)coords)[sp * 3 + 0];
        y = ((const float*)coords)[sp * 3 + 1];
        z = ((const float*)coords)[sp * 3 + 2];
    }

    Samp sx = make_samp(x, 128), sy = make_samp(y, 128), sz = make_samp(z, 128);
    Samp vx = make_samp(x, 64),  vy = make_samp(y, 64),  vz = make_samp(z, 64);

    float feat[4][2][4];
#pragma unroll
    for (int mt = 0; mt < 4; ++mt)
#pragma unroll
        for (int n = 0; n < 2; ++n)
#pragma unroll
            for (int r = 0; r < 4; ++r) feat[mt][n][r] = 0.0f;

    term_phase(lane, q, l15, lines_s + 0 * 4096, sx, planes_s + 1 * 524288, sy, sz,
               WtH + 0,    bv + 0,  bw, feat);
    term_phase(lane, q, l15, lines_s + 1 * 4096, sy, planes_s + 2 * 524288, sx, sz,
               WtH + 1024, bv + 32, bw, feat);
    term_phase(lane, q, l15, lines_s + 2 * 4096, sz, planes_s + 0 * 524288, sx, sy,
               WtH + 2048, bv + 64, bw, feat);

    // issue volume gathers now; they land under the E2-feat LDS phase
    VL V;
    vol_loads(vol_s, vx, vy, vz, V);

    // ---- E2 phase 1: feature cols 0..31 (k-halves from feat) ----
#pragma unroll
    for (int mt = 0; mt < 4; ++mt)
#pragma unroll
        for (int n = 0; n < 2; ++n)
#pragma unroll
            for (int r = 0; r < 4; ++r)
                bw[(mt * 16 + q * 4 + r) * SB + n * 16 + l15] =
                    (_Float16)feat[mt][n][r];
    lds_wait();
    h8v af0[4];
#pragma unroll
    for (int mt = 0; mt < 4; ++mt)
        af0[mt] = *(const h8v*)&bw[(mt * 16 + l15) * SB + q * 8];
    lds_wait();

    // ---- E2 phase 2: vol cols 32..39 + zero cols 40..63 (local 0..31) ----
    {
        float vf[8];
#pragma unroll
        for (int c = 0; c < 8; ++c) vf[c] = 0.0f;
#pragma unroll
        for (int corner = 0; corner < 8; ++corner) {
            int dx = corner & 1, dy = (corner >> 1) & 1, dz = corner >> 2;
            float w = (dx ? vx.w1 : vx.w0) * (dy ? vy.w1 : vy.w0)
                    * (dz ? vz.w1 : vz.w0);
            u16x8 v = V.v[corner];
#pragma unroll
            for (int c = 0; c < 8; ++c)
                vf[c] = fmaf(w, bf2f(v[c]), vf[c]);
        }
        H8 hv;
#pragma unroll
        for (int k = 0; k < 4; ++k) hv.p[k] = pk(vf[2 * k], vf[2 * k + 1]);
        *(h8v*)&bw[lane * SB + 0]  = hv.v;
        h8v zz = {};
        *(h8v*)&bw[lane * SB + 8]  = zz;
        *(h8v*)&bw[lane * SB + 16] = zz;
        *(h8v*)&bw[lane * SB + 24] = zz;
    }
    lds_wait();
    h8v af1[4];
#pragma unroll
    for (int mt = 0; mt < 4; ++mt)
        af1[mt] = *(const h8v*)&bw[(mt * 16 + l15) * SB + q * 8];

    // ---- second GEMM: 128-wide hidden layer ----
    float s[4][4];
#pragma unroll
    for (int mt = 0; mt < 4; ++mt)
#pragma unroll
        for (int r = 0; r < 4; ++r) s[mt][r] = 0.0f;

#pragma unroll
    for (int NT = 0; NT < 8; ++NT) {
        int o = NT * 16 + l15;
        h8v b0  = *(const h8v*)&W1H[o * 64 + q * 8];
        h8v b1f = *(const h8v*)&W1H[o * 64 + 32 + q * 8];
        float w2 = W2v[o];
        float bb = b1v[o];
        f4v cinit = {bb, bb, bb, bb};
#pragma unroll
        for (int mt = 0; mt < 4; ++mt) {
            f4v c = MFMA16(af0[mt], b0, cinit);
            c = MFMA16(af1[mt], b1f, c);
#pragma unroll
            for (int r = 0; r < 4; ++r)
                s[mt][r] = fmaf(fmaxf(c[r], 0.0f), w2, s[mt][r]);
        }
    }
#pragma unroll
    for (int mt = 0; mt < 4; ++mt)
#pragma unroll
        for (int r = 0; r < 4; ++r) {
            float v = s[mt][r];
            v += __shfl_xor(v, 1);
            v += __shfl_xor(v, 2);
            v += __shfl_xor(v, 4);
            v += __shfl_xor(v, 8);
            s[mt][r] = v;
        }
    if (l15 == 0) {
#pragma unroll
        for (int mt = 0; mt < 4; ++mt)
#pragma unroll
            for (int r = 0; r < 4; ++r)
                resw[mt * 16 + q * 4 + r] = s[mt][r];
    }
    lds_wait();
    float rr = resw[lane] + b2v[0];
    if (dt) ((float*)out)[sp] = rr;
    else    ((u16*)out)[sp] = f2bf(rr);
}

// =====================================================================
// fallback path (ws too small): weights-only prep + direct gathers
// =====================================================================
__global__ void kp_prep_weights_fb(
    const void* __restrict__ coords,
    const void* __restrict__ Wx, const void* __restrict__ bx,
    const void* __restrict__ Wy, const void* __restrict__ by,
    const void* __restrict__ Wz, const void* __restrict__ bz,
    const void* __restrict__ W1, const void* __restrict__ b1,
    const void* __restrict__ W2, const void* __restrict__ b2,
    float* __restrict__ wbase)
{
    int dt = detect_dt(coords);
    int t = blockIdx.x * blockDim.x + threadIdx.x;
    weights_work(dt, t, Wx, bx, Wy, by, Wz, bz, W1, b1, W2, b2, wbase);
}

__global__ __launch_bounds__(256) void kp_main_direct(
    const void* __restrict__ coords,
    const void* __restrict__ lx, const void* __restrict__ ly, const void* __restrict__ lz,
    const void* __restrict__ pxy, const void* __restrict__ pyz, const void* __restrict__ pxz,
    const void* __restrict__ vol,
    const float* __restrict__ wbase,
    void* __restrict__ out, int M)
{
    int dt = detect_dt(coords);
    const _Float16* WtH = (const _Float16*)wbase;
    const float*    bv  = wbase + 1536;
    const _Float16* W1H = (const _Float16*)(wbase + 1632);
    const float*    b1v = wbase + 5728;
    const float*    W2v = wbase + 5856;
    const float*    b2v = wbase + 5984;

    int p = blockIdx.x * 256 + threadIdx.x;
    p = min(p, M - 1);

    float x = gld(dt, coords, p * 3 + 0);
    float y = gld(dt, coords, p * 3 + 1);
    float z = gld(dt, coords, p * 3 + 2);

    Samp sx = make_samp(x, 128), sy = make_samp(y, 128), sz = make_samp(z, 128);

    float feat[40];
#pragma unroll
    for (int o = 0; o < 40; ++o) feat[o] = 0.0f;

    const void* Ls[3] = {lx, ly, lz};
    const void* Psv[3] = {pyz, pxz, pxy};
    Samp sl3[3] = {sx, sy, sz};
    Samp sa3[3] = {sy, sx, sx};
    Samp sb3[3] = {sz, sz, sy};
#pragma unroll 1
    for (int m = 0; m < 3; ++m) {
        float ta[32], tb[32];
        const float* bvt = bv + m * 32;
        const _Float16* Wt = WtH + m * 1024;
#pragma unroll
        for (int o = 0; o < 32; ++o) { ta[o] = bvt[o]; tb[o] = bvt[o]; }
        Samp sl = sl3[m], sa = sa3[m], sb = sb3[m];
        float w00 = sb.w0 * sa.w0, w01 = sb.w0 * sa.w1;
        float w10 = sb.w1 * sa.w0, w11 = sb.w1 * sa.w1;
        int i00 = sb.i0 * 128 + sa.i0, i01 = sb.i0 * 128 + sa.i1;
        int i10 = sb.i1 * 128 + sa.i0, i11 = sb.i1 * 128 + sa.i1;
#pragma unroll 1
        for (int c = 0; c < 32; ++c) {
            float el = sl.w0 * gld(dt, Ls[m], c * 128 + sl.i0)
                     + sl.w1 * gld(dt, Ls[m], c * 128 + sl.i1);
            float ep = w00 * gld(dt, Psv[m], c * 16384 + i00)
                     + w01 * gld(dt, Psv[m], c * 16384 + i01)
                     + w10 * gld(dt, Psv[m], c * 16384 + i10)
                     + w11 * gld(dt, Psv[m], c * 16384 + i11);
            float r1 = fmaxf(el, 0.0f), r2 = fmaxf(ep, 0.0f);
#pragma unroll
            for (int o = 0; o < 32; ++o) {
                float w = (float)Wt[o * 32 + c];
                ta[o] = fmaf(r1, w, ta[o]);
                tb[o] = fmaf(r2, w, tb[o]);
            }
        }
#pragma unroll
        for (int o = 0; o < 32; ++o) feat[o] = fmaf(ta[o], tb[o], feat[o]);
    }

    Samp vx = make_samp(x, 64), vy = make_samp(y, 64), vz = make_samp(z, 64);
#pragma unroll 1
    for (int corner = 0; corner < 8; ++corner) {
        int dx = corner & 1, dy = (corner >> 1) & 1, dz = corner >> 2;
        int xi = dx ? vx.i1 : vx.i0;
        int yi = dy ? vy.i1 : vy.i0;
        int zi = dz ? vz.i1 : vz.i0;
        float w = (dx ? vx.w1 : vx.w0) * (dy ? vy.w1 : vy.w0) * (dz ? vz.w1 : vz.w0);
        int pos = ((zi * 64) + yi) * 64 + xi;
#pragma unroll
        for (int c = 0; c < 8; ++c)
            feat[32 + c] = fmaf(w, gld(dt, vol, c * 262144 + pos), feat[32 + c]);
    }

    float acc_out = b2v[0];
#pragma unroll 2
    for (int j = 0; j < 128; ++j) {
        float acc = b1v[j];
        const _Float16* wr = W1H + j * 64;
#pragma unroll
        for (int i = 0; i < 40; ++i)
            acc = fmaf(feat[i], (float)wr[i], acc);
        acc_out = fmaf(fmaxf(acc, 0.0f), W2v[j], acc_out);
    }
    if (dt) ((float*)out)[p] = acc_out;
    else    ((u16*)out)[p] = f2bf(acc_out);
}

// =====================================================================
extern "C" void kernel_launch(void* const* d_in, const int* in_sizes, int n_in,
                              void* d_out, int out_size, void* d_ws, size_t ws_size,
                              hipStream_t stream) {
    const void* coords = d_in[0];
    const void* lx  = d_in[1];
    const void* ly  = d_in[2];
    const void* lz  = d_in[3];
    const void* pxy = d_in[4];
    const void* pyz = d_in[5];
    const void* pxz = d_in[6];
    const void* vol = d_in[7];
    const void* Wx  = d_in[8];
    const void* bx  = d_in[9];
    const void* Wy  = d_in[10];
    const void* by  = d_in[11];
    const void* Wz  = d_in[12];
    const void* bz  = d_in[13];
    const void* W1  = d_in[14];
    const void* b1  = d_in[15];
    const void* W2  = d_in[16];
    const void* b2  = d_in[17];

    int M = in_sizes[0] / 3;

    char* ws = (char*)d_ws;
    float*        wbase    = (float*)(ws + WF_OFF);
    u16*          planes_s = (u16*)(ws + PLANES_S_OFF);
    u16*          vol_s    = (u16*)(ws + VOL_S_OFF);
    u16*          lines_s  = (u16*)(ws + LINES_S_OFF);
    u16*          part     = (u16*)(ws + PART_OFF);
    unsigned int* tot      = (unsigned int*)(ws + TOT_OFF);
    int*          order    = (int*)(ws + ORDER_OFF);
    u16*          scoords  = (u16*)(ws + ORDER_OFF + (size_t)M * 4u);

    size_t need_sorted = (size_t)ORDER_OFF + (size_t)M * 4u + (size_t)M * 6u;

    if (ws_size >= need_sorted) {
        kp_prep_all<<<2100, 256, 0, stream>>>(coords, lx, ly, lz, pxy, pyz, pxz, vol,
                                              Wx, bx, Wy, by, Wz, bz, W1, b1, W2, b2,
                                              wbase, planes_s, vol_s, lines_s, part, M);
        kp_colscan<<<64, 64, 0, stream>>>(part, tot);
        kp_scatter_det<<<HBLOCKS, 256, 0, stream>>>(coords, part, tot, order,
                                                    scoords, M);
        int blocks128 = (M + 127) / 128;
        kp_main_mfma<<<blocks128, 128, 0, stream>>>(coords, order, scoords,
                                                    planes_s, vol_s,
                                                    lines_s, wbase, d_out, M);
    } else {
        int blocks = (M + 255) / 256;
        kp_prep_weights_fb<<<46, 256, 0, stream>>>(coords, Wx, bx, Wy, by, Wz, bz,
                                                   W1, b1, W2, b2, wbase);
        kp_main_direct<<<blocks, 256, 0, stream>>>(coords, lx, ly, lz, pxy, pyz, pxz,
                                                   vol, wbase, d_out, M);
    }
}

// Round 11
// 195.722 us; speedup vs baseline: 1.5943x; 1.0330x over previous
//
#include <hip/hip_runtime.h>

typedef unsigned short u16;
typedef u16 u16x8 __attribute__((ext_vector_type(8)));
typedef _Float16 half2 __attribute__((ext_vector_type(2)));
typedef _Float16 h8v __attribute__((ext_vector_type(8)));
typedef float f4v __attribute__((ext_vector_type(4)));

union H8 { h8v v; half2 p[4]; };

// ---------- bf16 helpers ----------
static __device__ __forceinline__ float bf2f(u16 u) {
    union { unsigned int i; float f; } v;
    v.i = ((unsigned int)u) << 16;
    return v.f;
}
static __device__ __forceinline__ u16 f2bf(float f) {
    union { float f; unsigned int i; } v;
    v.f = f;
    unsigned int x = v.i;
    x += 0x7fffu + ((x >> 16) & 1u);   // RNE
    return (u16)(x >> 16);
}
static __device__ __forceinline__ float gld(int dt, const void* p, int i) {
    return dt ? ((const float*)p)[i] : bf2f(((const u16*)p)[i]);
}
static __device__ __forceinline__ int detect_dt(const void* coords) {
    u16 v = ((const u16*)coords)[threadIdx.x & 63];
    int e = (v >> 7) & 0xFF;
    bool inr = (e >= 90) && (e <= 126);
    unsigned long long m = __ballot(inr);
    return (__popcll(m) >= 56) ? 0 : 1;   // 0=bf16, 1=f32
}
static __device__ __forceinline__ half2 pk(float a, float b) {
    return __builtin_bit_cast(half2, __builtin_amdgcn_cvt_pkrtz(a, b));
}

// LDS-only ordering for single-wave workgroups: waits DS ops WITHOUT
// draining vmcnt — the prefetched plane/vol gathers stay in flight.
static __device__ __forceinline__ void lds_wait() {
    asm volatile("s_waitcnt lgkmcnt(0)" ::: "memory");
}

// ---------- ws layout (bytes) ----------
#define WF_OFF        64u
#define PLANES_S_OFF  34304u         // 3*524288 u16
#define VOL_S_OFF     3180032u       // 2097152 u16
#define LINES_S_OFF   7374336u       // 12288 u16
#define WS_NEED       7398912u       // end of staged tables

// =====================================================================
// weight packing (f16 MFMA layouts)
// =====================================================================
static __device__ __forceinline__ void weights_work(
    int dt, int r,
    const void* Wx, const void* bx, const void* Wy, const void* by,
    const void* Wz, const void* bz, const void* W1, const void* b1,
    const void* W2, const void* b2, float* wbase)
{
    _Float16* WtH = (_Float16*)wbase;
    float*    bv  = wbase + 1536;
    _Float16* W1H = (_Float16*)(wbase + 1632);
    float*    b1v = wbase + 5728;
    float*    W2v = wbase + 5856;
    float*    b2v = wbase + 5984;
    if (r < 3072) {
        int m = r >> 10, idx = r & 1023;
        int o = idx >> 5, c = idx & 31;
        const void* s = (m == 0) ? Wx : (m == 1) ? Wy : Wz;
        WtH[r] = (_Float16)gld(dt, s, c * 32 + o);   // Wt[m][o][c] = W[c][o]
    } else if (r < 3168) {
        int q2 = r - 3072;
        int m = q2 >> 5, c = q2 & 31;
        const void* s = (m == 0) ? bx : (m == 1) ? by : bz;
        bv[q2] = gld(dt, s, c);
    } else if (r < 11360) {
        int idx = r - 3168;                 // j*64 + i
        int j = idx >> 6, i = idx & 63;
        W1H[idx] = (i < 40) ? (_Float16)gld(dt, W1, i * 128 + j) : (_Float16)0.0f;
    } else if (r < 11488) {
        b1v[r - 11360] = gld(dt, b1, r - 11360);
    } else if (r < 11616) {
        W2v[r - 11488] = gld(dt, W2, r - 11488);
    } else if (r == 11616) {
        b2v[0] = gld(dt, b2, 0);
    }
}

// =====================================================================
// fused prep: grid transpose (0..1797) + weights (1798..1843)
// (histogram branch removed — no sort pipeline anymore)
// =====================================================================
__global__ __launch_bounds__(256) void kp_prep_all(
    const void* __restrict__ coords,
    const void* __restrict__ lx, const void* __restrict__ ly,
    const void* __restrict__ lz,
    const void* __restrict__ pxy, const void* __restrict__ pyz,
    const void* __restrict__ pxz, const void* __restrict__ vol,
    const void* __restrict__ Wx, const void* __restrict__ bx,
    const void* __restrict__ Wy, const void* __restrict__ by,
    const void* __restrict__ Wz, const void* __restrict__ bz,
    const void* __restrict__ W1, const void* __restrict__ b1,
    const void* __restrict__ W2, const void* __restrict__ b2,
    float* __restrict__ wbase,
    u16* __restrict__ planes_s, u16* __restrict__ vol_s,
    u16* __restrict__ lines_s)
{
    int dt = detect_dt(coords);
    int blk = blockIdx.x;
    if (blk < 1798) {
        int t = blk * 256 + threadIdx.x;   // [0, 460288)
        u16x8 v;
        if (t < 196608) {                 // planes: 8 consecutive out u16
            int o = t * 8;
            int pl = o >> 19;
            int r  = o & 524287;
            int pos = r >> 5, c0 = r & 31;
            const void* src = (pl == 0) ? pxy : (pl == 1) ? pyz : pxz;
#pragma unroll
            for (int i = 0; i < 8; ++i)
                v[i] = dt ? f2bf(((const float*)src)[(c0 + i) * 16384 + pos])
                          : ((const u16*)src)[(c0 + i) * 16384 + pos];
            *(u16x8*)(planes_s + o) = v;
        } else if (t < 458752) {          // volume: thread = one pos, 8 channels
            int pos = t - 196608;
#pragma unroll
            for (int c = 0; c < 8; ++c)
                v[c] = dt ? f2bf(((const float*)vol)[c * 262144 + pos])
                          : ((const u16*)vol)[c * 262144 + pos];
            *(u16x8*)(vol_s + pos * 8) = v;
        } else {                          // lines
            int o = (t - 458752) * 8;
            int l = o >> 12, rr = o & 4095;
            int pos = rr >> 5, c0 = rr & 31;
            const void* src = (l == 0) ? lx : (l == 1) ? ly : lz;
#pragma unroll
            for (int i = 0; i < 8; ++i)
                v[i] = dt ? f2bf(((const float*)src)[(c0 + i) * 128 + pos])
                          : ((const u16*)src)[(c0 + i) * 128 + pos];
            *(u16x8*)(lines_s + o) = v;
        }
    } else {
        int r = (blk - 1798) * 256 + threadIdx.x;   // [0, 11776)
        weights_work(dt, r, Wx, bx, Wy, by, Wz, bz, W1, b1, W2, b2, wbase);
    }
}

// =====================================================================
// shared math
// =====================================================================
struct Samp { int i0, i1; float w0, w1; };

static __device__ __forceinline__ Samp make_samp(float g, int N) {
    float ix = (g + 1.0f) * 0.5f * (float)(N - 1);
    float fl = floorf(ix);
    float w  = ix - fl;
    int i  = (int)fl;
    int i1 = i + 1;
    float v0 = (i  >= 0 && i  < N) ? 1.0f : 0.0f;
    float v1 = (i1 >= 0 && i1 < N) ? 1.0f : 0.0f;
    Samp s;
    s.w0 = (1.0f - w) * v0;
    s.w1 = w * v1;
    s.i0 = min(max(i, 0), N - 1);
    s.i1 = min(max(i1, 0), N - 1);
    return s;
}

#define MFMA16(a, b, c) __builtin_amdgcn_mfma_f32_16x16x32_f16((a), (b), (c), 0, 0, 0)

// LDS strides (halves). SRE=40/SR2=72: row stride 80B keeps the h8v
// LDS ops 16B-aligned (ds_*_b128). R6: stride 68B broke alignment, -8%.
#define SRE 40
#define SR2 72

// register-staged plane gathers for ONE term: 16 x 16B (64 VGPR)
struct PL { u16x8 q00[4], q01[4], q10[4], q11[4]; };
struct VL { u16x8 v[8]; };

static __device__ __forceinline__ void plane_load(
    const u16* __restrict__ Ps, const Samp& sa, const Samp& sb, PL& P)
{
    const u16x8* p00 = (const u16x8*)(Ps + (sb.i0 * 128 + sa.i0) * 32);
    const u16x8* p01 = (const u16x8*)(Ps + (sb.i0 * 128 + sa.i1) * 32);
    const u16x8* p10 = (const u16x8*)(Ps + (sb.i1 * 128 + sa.i0) * 32);
    const u16x8* p11 = (const u16x8*)(Ps + (sb.i1 * 128 + sa.i1) * 32);
#pragma unroll
    for (int cc = 0; cc < 4; ++cc) {
        P.q00[cc] = p00[cc]; P.q01[cc] = p01[cc];
        P.q10[cc] = p10[cc]; P.q11[cc] = p11[cc];
    }
}

static __device__ __forceinline__ void vol_loads(
    const u16* __restrict__ vol_s, const Samp& vx, const Samp& vy,
    const Samp& vz, VL& V)
{
#pragma unroll
    for (int corner = 0; corner < 8; ++corner) {
        int dx = corner & 1, dy = (corner >> 1) & 1, dz = corner >> 2;
        int xi = dx ? vx.i1 : vx.i0;
        int yi = dy ? vy.i1 : vy.i0;
        int zi = dz ? vz.i1 : vz.i0;
        V.v[corner] = *(const u16x8*)(vol_s + (((zi * 64) + yi) * 64 + xi) * 8);
    }
}

// One product term (R5 structure) with next-term prefetch issued between
// the conv LDS-writes and the MFMA block, so the next plane/vol gathers'
// latency hides under this term's MFMA + the next term's line-interp.
// PRE: 1 = prefetch plane -> PN, 2 = prefetch volume -> V.
template<int PRE>
static __device__ __forceinline__ void term_step(
    int lane, int q, int l15,
    const u16* __restrict__ Ls, const Samp& sl,
    const PL& P, const Samp& sa, const Samp& sb,
    const _Float16* __restrict__ Wt, const float* __restrict__ bvt,
    _Float16* El, _Float16* Ep, float (&feat)[4][2][4],
    const u16* __restrict__ nps, const Samp& na, const Samp& nb, PL& PN,
    const u16* __restrict__ vol_s, const Samp& vx, const Samp& vy,
    const Samp& vz, VL& V)
{
    const u16x8* l0 = (const u16x8*)(Ls + sl.i0 * 32);
    const u16x8* l1 = (const u16x8*)(Ls + sl.i1 * 32);
    float w00 = sb.w0 * sa.w0, w01 = sb.w0 * sa.w1;
    float w10 = sb.w1 * sa.w0, w11 = sb.w1 * sa.w1;
#pragma unroll
    for (int cc = 0; cc < 4; ++cc) {
        u16x8 A0 = l0[cc], A1 = l1[cc];
        u16x8 Q00 = P.q00[cc], Q01 = P.q01[cc];
        u16x8 Q10 = P.q10[cc], Q11 = P.q11[cc];
        H8 hl, hp;
#pragma unroll
        for (int kk = 0; kk < 4; ++kk) {
            int k0 = 2 * kk, k1 = k0 + 1;
            float el0 = sl.w0 * bf2f(A0[k0]) + sl.w1 * bf2f(A1[k0]);
            float el1 = sl.w0 * bf2f(A0[k1]) + sl.w1 * bf2f(A1[k1]);
            float ep0 = w00 * bf2f(Q00[k0]) + w01 * bf2f(Q01[k0])
                      + w10 * bf2f(Q10[k0]) + w11 * bf2f(Q11[k0]);
            float ep1 = w00 * bf2f(Q00[k1]) + w01 * bf2f(Q01[k1])
                      + w10 * bf2f(Q10[k1]) + w11 * bf2f(Q11[k1]);
            hl.p[kk] = pk(fmaxf(el0, 0.0f), fmaxf(el1, 0.0f));
            hp.p[kk] = pk(fmaxf(ep0, 0.0f), fmaxf(ep1, 0.0f));
        }
        *(h8v*)&El[lane * SRE + cc * 8] = hl.v;
        *(h8v*)&Ep[lane * SRE + cc * 8] = hp.v;
    }
    // prefetch for the NEXT phase: issued before this term's MFMA, consumed
    // after it — latency hidden. lgkm-only fences keep these in flight.
    if constexpr (PRE == 1) plane_load(nps, na, nb, PN);
    if constexpr (PRE == 2) vol_loads(vol_s, vx, vy, vz, V);

    h8v bf0 = *(const h8v*)&Wt[(l15) * 32 + q * 8];
    h8v bf1 = *(const h8v*)&Wt[(16 + l15) * 32 + q * 8];
    float bb0 = bvt[l15], bb1 = bvt[16 + l15];
    f4v c0 = {bb0, bb0, bb0, bb0};
    f4v c1 = {bb1, bb1, bb1, bb1};
    lds_wait();
#pragma unroll
    for (int mt = 0; mt < 4; ++mt) {
        h8v aL = *(const h8v*)&El[(mt * 16 + l15) * SRE + q * 8];
        h8v aP = *(const h8v*)&Ep[(mt * 16 + l15) * SRE + q * 8];
        f4v ta0 = MFMA16(aL, bf0, c0);
        f4v tb0 = MFMA16(aP, bf0, c0);
        f4v ta1 = MFMA16(aL, bf1, c1);
        f4v tb1 = MFMA16(aP, bf1, c1);
#pragma unroll
        for (int r = 0; r < 4; ++r) {
            feat[mt][0][r] += ta0[r] * tb0[r];
            feat[mt][1][r] += ta1[r] * tb1[r];
        }
    }
    lds_wait();   // MFMA operand ds_reads retired before next term overwrites
}

// =====================================================================
// MFMA main — UNSORTED: reads coords[p] directly (coalesced), writes
// out[p] coalesced. No sort pipeline at all — trades gather locality
// (L2/L3 instead of L1/L2 on the 7MB tables; we have 88% HBM headroom)
// for removing histogram+colscan+scatter (~50us aux) and the scattered
// 2B out-write RMW (16MB). R5 prefetch structure intact.
// NOTE: plain __launch_bounds__(64) — a min-waves hint makes the
// allocator clamp VGPRs (R3: clamped to 64 -> 155 MB scratch spills).
// =====================================================================
__global__ __launch_bounds__(64) void kp_main_mfma(
    const void* __restrict__ coords,
    const u16* __restrict__ planes_s, const u16* __restrict__ vol_s,
    const u16* __restrict__ lines_s,
    const float* __restrict__ wbase,
    void* __restrict__ out, int M)
{
    __shared__ _Float16 eb[5120];   // El[64*40] | Ep[64*40]; reused as E2[64*72]
    __shared__ float res[64];
    int dt = detect_dt(coords);
    const _Float16* WtH = (const _Float16*)wbase;
    const float*    bv  = wbase + 1536;
    const _Float16* W1H = (const _Float16*)(wbase + 1632);
    const float*    b1v = wbase + 5728;
    const float*    W2v = wbase + 5856;
    const float*    b2v = wbase + 5984;

    int lane = threadIdx.x;
    int q = lane >> 4, l15 = lane & 15;
    _Float16* El = eb;
    _Float16* Ep = eb + 2560;
    _Float16* E2 = eb;

    int p = blockIdx.x * 64 + lane;
    p = min(p, M - 1);

    float x, y, z;
    if (dt == 0) {
        const u16* cu = (const u16*)coords;
        x = bf2f(cu[p * 3 + 0]);
        y = bf2f(cu[p * 3 + 1]);
        z = bf2f(cu[p * 3 + 2]);
    } else {
        x = ((const float*)coords)[p * 3 + 0];
        y = ((const float*)coords)[p * 3 + 1];
        z = ((const float*)coords)[p * 3 + 2];
    }

    Samp sx = make_samp(x, 128), sy = make_samp(y, 128), sz = make_samp(z, 128);

    float feat[4][2][4];
#pragma unroll
    for (int mt = 0; mt < 4; ++mt)
#pragma unroll
        for (int n = 0; n < 2; ++n)
#pragma unroll
            for (int r = 0; r < 4; ++r) feat[mt][n][r] = 0.0f;

    PL Pa, Pb;
    VL V;
    Samp vx, vy, vz;   // computed just before term 2 (keeps peak regs low)

    plane_load(planes_s + 1 * 524288, sy, sz, Pa);   // term0 plane (exposed)

    // term 0: line x, plane yz (Pa); prefetch term1 plane xz -> Pb
    term_step<1>(lane, q, l15, lines_s + 0 * 4096, sx, Pa, sy, sz,
                 WtH + 0, bv + 0, El, Ep, feat,
                 planes_s + 2 * 524288, sx, sz, Pb,
                 vol_s, sx, sx, sx, V);

    // term 1: line y, plane xz (Pb); prefetch term2 plane xy -> Pa
    term_step<1>(lane, q, l15, lines_s + 1 * 4096, sy, Pb, sx, sz,
                 WtH + 1024, bv + 32, El, Ep, feat,
                 planes_s + 0 * 524288, sx, sy, Pa,
                 vol_s, sx, sx, sx, V);

    vx = make_samp(x, 64); vy = make_samp(y, 64); vz = make_samp(z, 64);

    // term 2: line z, plane xy (Pa); prefetch volume corners -> V
    term_step<2>(lane, q, l15, lines_s + 2 * 4096, sz, Pa, sx, sy,
                 WtH + 2048, bv + 64, El, Ep, feat,
                 planes_s, sx, sy, Pb,
                 vol_s, vx, vy, vz, V);

    // ---- E2 assembly (feat + trilinear volume from V regs) ----
#pragma unroll
    for (int mt = 0; mt < 4; ++mt)
#pragma unroll
        for (int n = 0; n < 2; ++n)
#pragma unroll
            for (int r = 0; r < 4; ++r)
                E2[(mt * 16 + q * 4 + r) * SR2 + n * 16 + l15] =
                    (_Float16)feat[mt][n][r];
    {
        float vf[8];
#pragma unroll
        for (int c = 0; c < 8; ++c) vf[c] = 0.0f;
#pragma unroll
        for (int corner = 0; corner < 8; ++corner) {
            int dx = corner & 1, dy = (corner >> 1) & 1, dz = corner >> 2;
            float w = (dx ? vx.w1 : vx.w0) * (dy ? vy.w1 : vy.w0)
                    * (dz ? vz.w1 : vz.w0);
            u16x8 v = V.v[corner];
#pragma unroll
            for (int c = 0; c < 8; ++c)
                vf[c] = fmaf(w, bf2f(v[c]), vf[c]);
        }
        H8 hv;
#pragma unroll
        for (int k = 0; k < 4; ++k) hv.p[k] = pk(vf[2 * k], vf[2 * k + 1]);
        *(h8v*)&E2[lane * SR2 + 32] = hv.v;
        h8v zz = {};
        *(h8v*)&E2[lane * SR2 + 40] = zz;
        *(h8v*)&E2[lane * SR2 + 48] = zz;
        *(h8v*)&E2[lane * SR2 + 56] = zz;
    }
    lds_wait();

    h8v af[4][2];
#pragma unroll
    for (int mt = 0; mt < 4; ++mt)
#pragma unroll
        for (int ks = 0; ks < 2; ++ks)
            af[mt][ks] = *(const h8v*)&E2[(mt * 16 + l15) * SR2 + ks * 32 + q * 8];

    float s[4][4];
#pragma unroll
    for (int mt = 0; mt < 4; ++mt)
#pragma unroll
        for (int r = 0; r < 4; ++r) s[mt][r] = 0.0f;

#pragma unroll
    for (int NT = 0; NT < 8; ++NT) {
        int o = NT * 16 + l15;
        h8v b0  = *(const h8v*)&W1H[o * 64 + q * 8];
        h8v b1f = *(const h8v*)&W1H[o * 64 + 32 + q * 8];
        float w2 = W2v[o];
        float bb = b1v[o];
        f4v cinit = {bb, bb, bb, bb};
#pragma unroll
        for (int mt = 0; mt < 4; ++mt) {
            f4v c = MFMA16(af[mt][0], b0, cinit);
            c = MFMA16(af[mt][1], b1f, c);
#pragma unroll
            for (int r = 0; r < 4; ++r)
                s[mt][r] = fmaf(fmaxf(c[r], 0.0f), w2, s[mt][r]);
        }
    }
#pragma unroll
    for (int mt = 0; mt < 4; ++mt)
#pragma unroll
        for (int r = 0; r < 4; ++r) {
            float v = s[mt][r];
            v += __shfl_xor(v, 1);
            v += __shfl_xor(v, 2);
            v += __shfl_xor(v, 4);
            v += __shfl_xor(v, 8);
            s[mt][r] = v;
        }
    if (l15 == 0) {
#pragma unroll
        for (int mt = 0; mt < 4; ++mt)
#pragma unroll
            for (int r = 0; r < 4; ++r)
                res[mt * 16 + q * 4 + r] = s[mt][r];
    }
    lds_wait();
    float rr = res[lane] + b2v[0];
    if (dt) ((float*)out)[p] = rr;      // coalesced
    else    ((u16*)out)[p]   = f2bf(rr); // coalesced
}

// =====================================================================
// fallback path (ws too small): weights-only prep + direct gathers
// =====================================================================
__global__ void kp_prep_weights_fb(
    const void* __restrict__ coords,
    const void* __restrict__ Wx, const void* __restrict__ bx,
    const void* __restrict__ Wy, const void* __restrict__ by,
    const void* __restrict__ Wz, const void* __restrict__ bz,
    const void* __restrict__ W1, const void* __restrict__ b1,
    const void* __restrict__ W2, const void* __restrict__ b2,
    float* __restrict__ wbase)
{
    int dt = detect_dt(coords);
    int t = blockIdx.x * blockDim.x + threadIdx.x;
    weights_work(dt, t, Wx, bx, Wy, by, Wz, bz, W1, b1, W2, b2, wbase);
}

__global__ __launch_bounds__(256) void kp_main_direct(
    const void* __restrict__ coords,
    const void* __restrict__ lx, const void* __restrict__ ly, const void* __restrict__ lz,
    const void* __restrict__ pxy, const void* __restrict__ pyz, const void* __restrict__ pxz,
    const void* __restrict__ vol,
    const float* __restrict__ wbase,
    void* __restrict__ out, int M)
{
    int dt = detect_dt(coords);
    const _Float16* WtH = (const _Float16*)wbase;
    const float*    bv  = wbase + 1536;
    const _Float16* W1H = (const _Float16*)(wbase + 1632);
    const float*    b1v = wbase + 5728;
    const float*    W2v = wbase + 5856;
    const float*    b2v = wbase + 5984;

    int p = blockIdx.x * 256 + threadIdx.x;
    p = min(p, M - 1);

    float x = gld(dt, coords, p * 3 + 0);
    float y = gld(dt, coords, p * 3 + 1);
    float z = gld(dt, coords, p * 3 + 2);

    Samp sx = make_samp(x, 128), sy = make_samp(y, 128), sz = make_samp(z, 128);

    float feat[40];
#pragma unroll
    for (int o = 0; o < 40; ++o) feat[o] = 0.0f;

    const void* Ls[3] = {lx, ly, lz};
    const void* Psv[3] = {pyz, pxz, pxy};
    Samp sl3[3] = {sx, sy, sz};
    Samp sa3[3] = {sy, sx, sx};
    Samp sb3[3] = {sz, sz, sy};
#pragma unroll 1
    for (int m = 0; m < 3; ++m) {
        float ta[32], tb[32];
        const float* bvt = bv + m * 32;
        const _Float16* Wt = WtH + m * 1024;
#pragma unroll
        for (int o = 0; o < 32; ++o) { ta[o] = bvt[o]; tb[o] = bvt[o]; }
        Samp sl = sl3[m], sa = sa3[m], sb = sb3[m];
        float w00 = sb.w0 * sa.w0, w01 = sb.w0 * sa.w1;
        float w10 = sb.w1 * sa.w0, w11 = sb.w1 * sa.w1;
        int i00 = sb.i0 * 128 + sa.i0, i01 = sb.i0 * 128 + sa.i1;
        int i10 = sb.i1 * 128 + sa.i0, i11 = sb.i1 * 128 + sa.i1;
#pragma unroll 1
        for (int c = 0; c < 32; ++c) {
            float el = sl.w0 * gld(dt, Ls[m], c * 128 + sl.i0)
                     + sl.w1 * gld(dt, Ls[m], c * 128 + sl.i1);
            float ep = w00 * gld(dt, Psv[m], c * 16384 + i00)
                     + w01 * gld(dt, Psv[m], c * 16384 + i01)
                     + w10 * gld(dt, Psv[m], c * 16384 + i10)
                     + w11 * gld(dt, Psv[m], c * 16384 + i11);
            float r1 = fmaxf(el, 0.0f), r2 = fmaxf(ep, 0.0f);
#pragma unroll
            for (int o = 0; o < 32; ++o) {
                float w = (float)Wt[o * 32 + c];
                ta[o] = fmaf(r1, w, ta[o]);
                tb[o] = fmaf(r2, w, tb[o]);
            }
        }
#pragma unroll
        for (int o = 0; o < 32; ++o) feat[o] = fmaf(ta[o], tb[o], feat[o]);
    }

    Samp vx = make_samp(x, 64), vy = make_samp(y, 64), vz = make_samp(z, 64);
#pragma unroll 1
    for (int corner = 0; corner < 8; ++corner) {
        int dx = corner & 1, dy = (corner >> 1) & 1, dz = corner >> 2;
        int xi = dx ? vx.i1 : vx.i0;
        int yi = dy ? vy.i1 : vy.i0;
        int zi = dz ? vz.i1 : vz.i0;
        float w = (dx ? vx.w1 : vx.w0) * (dy ? vy.w1 : vy.w0) * (dz ? vz.w1 : vz.w0);
        int pos = ((zi * 64) + yi) * 64 + xi;
#pragma unroll
        for (int c = 0; c < 8; ++c)
            feat[32 + c] = fmaf(w, gld(dt, vol, c * 262144 + pos), feat[32 + c]);
    }

    float acc_out = b2v[0];
#pragma unroll 2
    for (int j = 0; j < 128; ++j) {
        float acc = b1v[j];
        const _Float16* wr = W1H + j * 64;
#pragma unroll
        for (int i = 0; i < 40; ++i)
            acc = fmaf(feat[i], (float)wr[i], acc);
        acc_out = fmaf(fmaxf(acc, 0.0f), W2v[j], acc_out);
    }
    if (dt) ((float*)out)[p] = acc_out;
    else    ((u16*)out)[p] = f2bf(acc_out);
}

// =====================================================================
extern "C" void kernel_launch(void* const* d_in, const int* in_sizes, int n_in,
                              void* d_out, int out_size, void* d_ws, size_t ws_size,
                              hipStream_t stream) {
    const void* coords = d_in[0];
    const void* lx  = d_in[1];
    const void* ly  = d_in[2];
    const void* lz  = d_in[3];
    const void* pxy = d_in[4];
    const void* pyz = d_in[5];
    const void* pxz = d_in[6];
    const void* vol = d_in[7];
    const void* Wx  = d_in[8];
    const void* bx  = d_in[9];
    const void* Wy  = d_in[10];
    const void* by  = d_in[11];
    const void* Wz  = d_in[12];
    const void* bz  = d_in[13];
    const void* W1  = d_in[14];
    const void* b1  = d_in[15];
    const void* W2  = d_in[16];
    const void* b2  = d_in[17];

    int M = in_sizes[0] / 3;

    char* ws = (char*)d_ws;
    float* wbase    = (float*)(ws + WF_OFF);
    u16*   planes_s = (u16*)(ws + PLANES_S_OFF);
    u16*   vol_s    = (u16*)(ws + VOL_S_OFF);
    u16*   lines_s  = (u16*)(ws + LINES_S_OFF);

    if (ws_size >= (size_t)WS_NEED) {
        kp_prep_all<<<1844, 256, 0, stream>>>(coords, lx, ly, lz, pxy, pyz, pxz, vol,
                                              Wx, bx, Wy, by, Wz, bz, W1, b1, W2, b2,
                                              wbase, planes_s, vol_s, lines_s);
        int blocks64 = (M + 63) / 64;
        kp_main_mfma<<<blocks64, 64, 0, stream>>>(coords, planes_s, vol_s, lines_s,
                                                  wbase, d_out, M);
    } else {
        int blocks = (M + 255) / 256;
        kp_prep_weights_fb<<<46, 256, 0, stream>>>(coords, Wx, bx, Wy, by, Wz, bz,
                                                   W1, b1, W2, b2, wbase);
        kp_main_direct<<<blocks, 256, 0, stream>>>(coords, lx, ly, lz, pxy, pyz, pxz,
                                                   vol, wbase, d_out, M);
    }
}